// Round 9
// baseline (202.760 us; speedup 1.0000x reference)
//
#include <hip/hip_runtime.h>

typedef __attribute__((ext_vector_type(8))) short short8;
typedef __attribute__((ext_vector_type(4))) float f32x4;
typedef __attribute__((ext_vector_type(4))) float float4v;
typedef __attribute__((ext_vector_type(4))) unsigned int u32x4;

__device__ __forceinline__ unsigned short f2bf(float f) {
    unsigned int u = __float_as_uint(f);
    u += 0x7fffu + ((u >> 16) & 1u);
    return (unsigned short)(u >> 16);
}

__device__ __forceinline__ float wavesum(float x) {
#pragma unroll
    for (int m = 1; m < 64; m <<= 1) x += __shfl_xor(x, m);
    return x;
}

__device__ __forceinline__ float wavemax(float x) {
#pragma unroll
    for (int m = 1; m < 64; m <<= 1) x = fmaxf(x, __shfl_xor(x, m));
    return x;
}

// dot(row[0..63], y-distributed-one-per-lane) via readlane broadcasts.
__device__ __forceinline__ float matvec64(const float* row, float y) {
    float ac[8] = {0.f, 0.f, 0.f, 0.f, 0.f, 0.f, 0.f, 0.f};
#pragma unroll
    for (int j = 0; j < 64; ++j) {
        const float yj =
            __uint_as_float(__builtin_amdgcn_readlane(__float_as_uint(y), j));
        ac[j & 7] = fmaf(row[j], yj, ac[j & 7]);
    }
    return ((ac[0] + ac[1]) + (ac[2] + ac[3])) + ((ac[4] + ac[5]) + (ac[6] + ac[7]));
}

#define WTF_OFF       81920
#define WTOLD_OFF     745472
#define WS_NEEDED     1409024UL

// fm LDS layout (bytes):
#define FM_AFP   0        // fp32 [64][68] = 17408
#define FM_R0    17408    // fp32 [64][68]
#define FM_R1    34816    // fp32 [64][68]
#define FM_SLOT  52224    // 3 slots x 4096 half (8192 B each) = 24576
#define FM_RED   76800    // 4 float wave-max + sigma
#define FM_SMEM  76928

// ---------------------------------------------------------------------------
// One 64x64x64 matmul on 4 waves (t<256), single-bf16 operands, fp32 acc.
// (Validated round 6.)
// ---------------------------------------------------------------------------
__device__ __forceinline__ void fm_matmul_sb(char* sm, int srcOff, int bfSrcSlot,
                                             int dstOff, int bfDstSlot, int t) {
    const float* src = (const float*)(sm + srcOff);
    const unsigned short* bfS =
        (const unsigned short*)(sm + FM_SLOT) + bfSrcSlot * 4096;
    float* dst = (float*)(sm + dstOff);
    float* redf = (float*)(sm + FM_RED);
    const int lane = t & 63;
    const int wv = t >> 6;
    const int lm = lane & 15, lg = lane >> 4;
    f32x4 acc[4] = {};
    if (t < 256) {
#pragma unroll
        for (int kk = 0; kk < 2; ++kk) {
            const float* ap = src + (16 * wv + lm) * 68 + kk * 32 + lg * 8;
            const f32x4 a0 = *(const f32x4*)ap;
            const f32x4 a1 = *(const f32x4*)(ap + 4);
            short8 ah;
#pragma unroll
            for (int j = 0; j < 4; ++j) {
                ah[j] = (short)f2bf(a0[j]);
                ah[j + 4] = (short)f2bf(a1[j]);
            }
#pragma unroll
            for (int cf = 0; cf < 4; ++cf) {
                const short8 b =
                    *(const short8*)(bfS + ((kk * 4 + cf) * 64 + lane) * 8);
                acc[cf] = __builtin_amdgcn_mfma_f32_16x16x32_bf16(ah, b, acc[cf],
                                                                  0, 0, 0);
            }
        }
        float mx = 0.0f;
#pragma unroll
        for (int cf = 0; cf < 4; ++cf)
#pragma unroll
            for (int r = 0; r < 4; ++r) mx = fmaxf(mx, fabsf(acc[cf][r]));
        mx = wavemax(mx);
        if (lane == 0) redf[wv] = mx;
    }
    __syncthreads();
    if (t < 256) {
        const float g = fmaxf(fmaxf(redf[0], redf[1]), fmaxf(redf[2], redf[3]));
        const float sc = 1.0f / g;
        unsigned short* bfD = (unsigned short*)(sm + FM_SLOT) + bfDstSlot * 4096;
#pragma unroll
        for (int cf = 0; cf < 4; ++cf) {
#pragma unroll
            for (int r = 0; r < 4; ++r) {
                const int k = 16 * wv + 4 * lg + r;
                const int nn = 16 * cf + lm;
                const float v = acc[cf][r] * sc;
                dst[k * 68 + nn] = v;
                if (bfDstSlot >= 0)
                    bfD[(((k >> 5) * 4 + cf) * 64 + ((k & 31) >> 3) * 16 + lm) * 8 +
                        (k & 7)] = f2bf(v);
            }
        }
    }
    __syncthreads();
}

// ---------------------------------------------------------------------------
// fm kernel (5 blocks): matrix-power sigma + MFMA bf16x3 Taylor. (Validated.)
// ---------------------------------------------------------------------------
__global__ __launch_bounds__(512) void fm_kernel(const float* __restrict__ W,
                                                 const float* __restrict__ u0,
                                                 float* __restrict__ FmOut) {
    __shared__ __align__(16) char smem[FM_SMEM];
    const int t = threadIdx.x;
    float* Afp = (float*)(smem + FM_AFP);
    float* R0f = (float*)(smem + FM_R0);
    float* R1f = (float*)(smem + FM_R1);
    float* redf = (float*)(smem + FM_RED);
    float* sigP = redf + 4;
    const int n = blockIdx.x;
    const int lane = t & 63;
    const int wv = t >> 6;
    const int lm = lane & 15, lg = lane >> 4;

    {
        const int i = t >> 3;
        const int j0 = (t & 7) * 8;
#pragma unroll
        for (int k = 0; k < 8; ++k) {
            const int j = j0 + k;
            const float wij = W[(i * 64 + j) * 5 + n];
            const float wji = W[(j * 64 + i) * 5 + n];
            Afp[i * 68 + j] = 0.5f * (wij - wji);
        }
    }
    __syncthreads();

    if (t < 256) {
        unsigned short* s0 = (unsigned short*)(smem + FM_SLOT);
#pragma unroll
        for (int cf = 0; cf < 4; ++cf) {
#pragma unroll
            for (int r = 0; r < 4; ++r) {
                const int k = 16 * wv + 4 * lg + r;
                const int nn = 16 * cf + lm;
                s0[(((k >> 5) * 4 + cf) * 64 + ((k & 31) >> 3) * 16 + lm) * 8 +
                   (k & 7)] = f2bf(Afp[k * 68 + nn]);
            }
        }
    }
    __syncthreads();

    fm_matmul_sb(smem, FM_AFP, 0, FM_R0, 1, t);  // M
    fm_matmul_sb(smem, FM_R0, 1, FM_R1, 2, t);   // M2
    fm_matmul_sb(smem, FM_R1, 2, FM_R0, 0, t);   // M4
    fm_matmul_sb(smem, FM_R0, 0, FM_R1, 2, t);   // M8
    fm_matmul_sb(smem, FM_R1, 2, FM_R0, 0, t);   // M16
    fm_matmul_sb(smem, FM_R0, 0, FM_R1, -1, t);  // M32
    fm_matmul_sb(smem, FM_R1, 0, FM_R0, -1, t);  // M48
    fm_matmul_sb(smem, FM_R0, 1, FM_R1, -1, t);  // M49

    if (t < 64) {
        float row[64];
#pragma unroll
        for (int q = 0; q < 16; ++q)
            *(f32x4*)&row[q * 4] = *(const f32x4*)&R1f[t * 68 + q * 4];
        float u = u0[n * 64 + t];
        u = u / (sqrtf(wavesum(u * u)) + 1e-12f);
        const float w = matvec64(row, u);
#pragma unroll
        for (int q = 0; q < 16; ++q)
            *(f32x4*)&row[q * 4] = *(const f32x4*)&Afp[t * 68 + q * 4];
        const float tt = matvec64(row, w);
        const float v = tt / (sqrtf(wavesum(tt * tt)) + 1e-12f);
        const float s = matvec64(row, v);
        const float u50 = -s / (sqrtf(wavesum(s * s)) + 1e-12f);
        const float t2 = matvec64(row, u50);
        const float sig = wavesum(v * t2);
        if (t == 0) *sigP = sig;
    }
    __syncthreads();

    const float inv_sig = 1.0f / (*sigP);
    float Fm[4][4];
    if (t < 256) {
        unsigned int* Anpk = (unsigned int*)(smem + FM_SLOT);
#pragma unroll
        for (int cf = 0; cf < 4; ++cf) {
#pragma unroll
            for (int r = 0; r < 4; ++r) {
                const int k = 16 * wv + 4 * lg + r;
                const int nn = 16 * cf + lm;
                const float v = Afp[k * 68 + nn] * inv_sig;
                R0f[k * 68 + nn] = v;
                const unsigned int ph = f2bf(v);
                const float hf = __uint_as_float(ph << 16);
                const unsigned int pl = f2bf(v - hf);
                Anpk[(((k >> 5) * 4 + cf) * 64 + ((k & 31) >> 3) * 16 + lm) * 8 +
                     (k & 7)] = ph | (pl << 16);
                Fm[cf][r] = v;
            }
        }
    }
    __syncthreads();

    for (int term = 2; term <= 10; ++term) {
        f32x4 acc[4] = {};
        if (t < 256) {
            const unsigned int* Anpk = (const unsigned int*)(smem + FM_SLOT);
#pragma unroll
            for (int kk = 0; kk < 2; ++kk) {
                const float* ap = R0f + (16 * wv + lm) * 68 + kk * 32 + lg * 8;
                const f32x4 a0 = *(const f32x4*)ap;
                const f32x4 a1 = *(const f32x4*)(ap + 4);
                short8 ah, al;
#pragma unroll
                for (int j = 0; j < 4; ++j) {
                    const unsigned int h0 = f2bf(a0[j]);
                    ah[j] = (short)h0;
                    al[j] = (short)f2bf(a0[j] - __uint_as_float(h0 << 16));
                    const unsigned int h1 = f2bf(a1[j]);
                    ah[j + 4] = (short)h1;
                    al[j + 4] = (short)f2bf(a1[j] - __uint_as_float(h1 << 16));
                }
#pragma unroll
                for (int cf = 0; cf < 4; ++cf) {
                    const unsigned int* pp = Anpk + ((kk * 4 + cf) * 64 + lane) * 8;
                    const u32x4 p0 = *(const u32x4*)pp;
                    const u32x4 p1 = *(const u32x4*)(pp + 4);
                    short8 bh, bl;
#pragma unroll
                    for (int j = 0; j < 4; ++j) {
                        bh[j] = (short)(p0[j] & 0xffffu);
                        bl[j] = (short)(p0[j] >> 16);
                        bh[j + 4] = (short)(p1[j] & 0xffffu);
                        bl[j + 4] = (short)(p1[j] >> 16);
                    }
                    acc[cf] = __builtin_amdgcn_mfma_f32_16x16x32_bf16(ah, bh,
                                                                      acc[cf], 0, 0, 0);
                    acc[cf] = __builtin_amdgcn_mfma_f32_16x16x32_bf16(ah, bl,
                                                                      acc[cf], 0, 0, 0);
                    acc[cf] = __builtin_amdgcn_mfma_f32_16x16x32_bf16(al, bh,
                                                                      acc[cf], 0, 0, 0);
                }
            }
        }
        __syncthreads();
        if (t < 256) {
            const float sc = 1.0f / (float)term;
#pragma unroll
            for (int cf = 0; cf < 4; ++cf) {
#pragma unroll
                for (int r = 0; r < 4; ++r) {
                    const int k = 16 * wv + 4 * lg + r;
                    const int nn = 16 * cf + lm;
                    const float v = acc[cf][r] * sc;
                    Fm[cf][r] += v;
                    if (term < 10) R0f[k * 68 + nn] = v;
                }
            }
        }
        __syncthreads();
    }

    if (t < 256) {
#pragma unroll
        for (int cf = 0; cf < 4; ++cf) {
#pragma unroll
            for (int r = 0; r < 4; ++r) {
                const int k = 16 * wv + 4 * lg + r;
                const int nn = 16 * cf + lm;
                FmOut[n * 4096 + k * 64 + nn] = Fm[cf][r] + ((k == nn) ? 1.0f : 0.0f);
            }
        }
    }
}

// ---------------------------------------------------------------------------
// wbuild: Fm -> 3x3 real-ifft -> folded weight; Wtf (16x16 A-frag order) and
// WtOld ([m][kap]) for the fallback path. (Unchanged.)
// ---------------------------------------------------------------------------
__global__ __launch_bounds__(256) void wbuild_kernel(const float* __restrict__ Fm,
                                                     unsigned short* __restrict__ Wtf,
                                                     unsigned short* __restrict__ WtOld) {
    const int tg = blockIdx.x * 256 + threadIdx.x;
    const int o = tg >> 6;
    const int i = tg & 63;
    float f[5];
#pragma unroll
    for (int nn = 0; nn < 5; ++nn) f[nn] = Fm[nn * 4096 + o * 64 + i];
    const int idx[3][3] = {{0, 1, 1}, {2, 3, 4}, {2, 4, 3}};
    float Kk[3][3];
#pragma unroll
    for (int u = 0; u < 3; ++u) {
#pragma unroll
        for (int v = 0; v < 3; ++v) {
            float s = 0.0f;
#pragma unroll
            for (int p = 0; p < 3; ++p) {
#pragma unroll
                for (int q = 0; q < 3; ++q) {
                    const int m = (p * u + q * v) % 3;
                    s += f[idx[p][q]] * ((m == 0) ? 1.0f : -0.5f);
                }
            }
            Kk[u][v] = s * (1.0f / 9.0f);
        }
    }
#pragma unroll
    for (int a = 0; a < 3; ++a) {
#pragma unroll
        for (int b = 0; b < 3; ++b) {
            const int m = (a * 3 + b) * 64 + o;
#pragma unroll
            for (int al = 0; al < 3; ++al) {
#pragma unroll
                for (int be = 0; be < 3; ++be) {
                    const int kh = (al - a + 4) % 3;
                    const int kw = (be - b + 4) % 3;
                    const unsigned short bf = f2bf(Kk[kh][kw]);
                    const int kap = (al * 3 + be) * 64 + i;
                    WtOld[m * 576 + kap] = bf;
                    const int MF = m >> 4, lmx = m & 15;
                    const int cc = kap >> 5, lgx = (kap >> 3) & 3, j = kap & 7;
                    Wtf[MF * 9216 + cc * 512 + (lgx * 16 + lmx) * 8 + j] = bf;
                }
            }
        }
    }
}

// ---------------------------------------------------------------------------
// gemm6: fully reg-staged pipeline, 2-deep on B.
//   chunk c: B regs in RS[c&1], LDS buf c&1.
//   iter kc: BLOAD(kc+2) -> RS[kc&1]; COMPUTE(kc&1);
//            BSTORE+ASTORE chunk kc+1 -> buf (kc+1)&1 (loads 1+ iter old);
//            ALOAD(kc+2) -> WA; barrier.
// No global_load_lds => no forced vmcnt(0) at barriers; B consumption gap
// ~2 COMPUTE phases covers HBM latency. Values bit-identical to gemm5.
// ---------------------------------------------------------------------------
__global__ __launch_bounds__(256, 2) void gemm6_kernel(
    const float* __restrict__ x, const unsigned short* __restrict__ Wtf,
    const float* __restrict__ bias, float* __restrict__ out) {
    __shared__ __align__(16) char smem[81920];
    const int t = threadIdx.x;
    const int lane = t & 63;
    const int wv = t >> 6;
    const int wm = wv >> 1;
    const int wp = wv & 1;
    const int lm = lane & 15;
    const int lg = lane >> 4;

    const int orig = blockIdx.x;
    const int swz = (orig & 7) * 192 + (orig >> 3);
    const int mg = swz % 3;
    const int panel = swz / 3;
    const int n = panel >> 5;
    const int h0b = (panel & 31) * 2;

    // B-region bank swizzle offsets (write / read, same involution — T2)
    const int sswz = (wv ^ ((lane >> 1) & 3)) * 16;  // store: p=(j&1)*64+lane
    const int rswz = (lg ^ ((lm >> 1) & 3)) * 16;    // read: p'=wp*64+pf*16+lm

    f32x4 acc[6][4] = {};
    float RS0[4][8], RS1[4][8];
    u32x4 WA[6];

    const float* xb = x + (size_t)n * 2359296 + lane;

#define BLOAD(KC, RS)                                                           \
    {                                                                           \
        const int al_ = (KC) / 3, be_ = (KC) - 3 * ((KC) / 3);                  \
        const float* xc = xb + (h0b + 64 * al_) * 192 + be_ * 64;               \
        _Pragma("unroll") for (int j = 0; j < 4; ++j)                           \
            _Pragma("unroll") for (int k = 0; k < 8; ++k)                       \
                RS[j][k] = xc[(size_t)((j >> 1) * 32 + wv * 8 + k) * 36864 +    \
                              (j & 1) * 192];                                   \
    }

#define BSTORE(BUF, RS)                                                         \
    {                                                                           \
        _Pragma("unroll") for (int j = 0; j < 4; ++j) {                         \
            union { unsigned short us[8]; short8 v; } pk;                       \
            _Pragma("unroll") for (int k = 0; k < 8; ++k)                       \
                pk.us[k] = f2bf(RS[j][k]);                                      \
            *(short8*)(smem + (BUF) * 40960 + 24576 + (j >> 1) * 8192 +         \
                       ((j & 1) * 64 + lane) * 64 + sswz) = pk.v;               \
        }                                                                       \
    }

#define ALOAD(KC)                                                               \
    {                                                                           \
        _Pragma("unroll") for (int it = 0; it < 6; ++it) {                      \
            const int e = it * 2048 + t * 8;                                    \
            const int mfL = e >> 10;                                            \
            const int rem = e & 1023;                                           \
            WA[it] = *(const u32x4*)(Wtf + (mg * 12 + mfL) * 9216 +             \
                                     (KC) * 1024 + rem);                        \
        }                                                                       \
    }

#define ASTORE(BUF)                                                             \
    {                                                                           \
        _Pragma("unroll") for (int it = 0; it < 6; ++it)                        \
            *(u32x4*)(smem + (BUF) * 40960 + it * 4096 + t * 16) = WA[it];      \
    }

#define COMPUTE(BUF)                                                            \
    {                                                                           \
        const char* base = smem + (BUF) * 40960;                                \
        short8 af[12];                                                          \
        short8 bf[8];                                                           \
        _Pragma("unroll") for (int mf = 0; mf < 6; ++mf)                        \
            _Pragma("unroll") for (int cl = 0; cl < 2; ++cl)                    \
                af[mf * 2 + cl] = *(const short8*)(                             \
                    base + (wm * 6 + mf) * 2048 + cl * 1024 + lane * 16);       \
        _Pragma("unroll") for (int pf = 0; pf < 4; ++pf)                        \
            _Pragma("unroll") for (int cl = 0; cl < 2; ++cl)                    \
                bf[pf * 2 + cl] = *(const short8*)(                             \
                    base + 24576 + cl * 8192 +                                  \
                    (wp * 64 + pf * 16 + lm) * 64 + rswz);                      \
        _Pragma("unroll") for (int cl = 0; cl < 2; ++cl)                        \
            _Pragma("unroll") for (int mf = 0; mf < 6; ++mf)                    \
                _Pragma("unroll") for (int pf = 0; pf < 4; ++pf)                \
                    acc[mf][pf] = __builtin_amdgcn_mfma_f32_16x16x32_bf16(      \
                        af[mf * 2 + cl], bf[pf * 2 + cl], acc[mf][pf], 0, 0, 0);\
    }

    // prologue: chunk0 -> buf0 (one-time drain), then chunk1 loads in flight
    BLOAD(0, RS0);
    ALOAD(0);
    BSTORE(0, RS0);
    ASTORE(0);
    ALOAD(1);
    BLOAD(1, RS1);
    __syncthreads();

#pragma unroll
    for (int kc = 0; kc < 9; ++kc) {
        const int b = kc & 1;
        if (kc < 7) {
            if (b) { BLOAD(kc + 2, RS1); } else { BLOAD(kc + 2, RS0); }
        }
        COMPUTE(b);
        if (kc < 8) {
            if (b) { BSTORE(b ^ 1, RS0); } else { BSTORE(b ^ 1, RS1); }
            ASTORE(b ^ 1);
            if (kc < 7) ALOAD(kc + 2);
            __syncthreads();
        }
    }
#undef BLOAD
#undef BSTORE
#undef ALOAD
#undef ASTORE
#undef COMPUTE

    const int h0 = h0b + wp;
#pragma unroll
    for (int mf = 0; mf < 6; ++mf) {
#pragma unroll
        for (int r = 0; r < 4; ++r) {
            const int m = mg * 192 + wm * 96 + mf * 16 + lg * 4 + r;
            const int o = m & 63;
            const int ab2 = m >> 6;
            const float bo = bias[o];
            const int rowoff =
                ((n * 64 + o) * 192 + (h0 + 64 * (ab2 / 3))) * 192 + 64 * (ab2 % 3);
#pragma unroll
            for (int pf = 0; pf < 4; ++pf) {
                out[rowoff + pf * 16 + lm] = acc[mf][pf][r] + bo;
            }
        }
    }
}

// ---------------------------------------------------------------------------
// Fallback GEMM (round-1 validated, LDS-staged fp32) if ws is tiny.
// ---------------------------------------------------------------------------
__global__ __launch_bounds__(256) void gemm_fallback(const float* __restrict__ x,
                                                     const unsigned short* __restrict__ Wt,
                                                     const float* __restrict__ bias,
                                                     float* __restrict__ out) {
    __shared__ unsigned short Xs[64][36];
    const int t = threadIdx.x;
    const int lane = t & 63;
    const int wv = t >> 6;
    const int pblk = blockIdx.x;
    const int mg = blockIdx.y;
    const int n = pblk >> 6;
    const int h0 = pblk & 63;
    const int wave_m0 = mg * 192 + wv * 48;
    const int lm = lane & 15;
    const int lg = lane >> 4;

    f32x4 acc[3][4] = {};
    const float* xb = x + n * 64 * 36864;
    const int w0s = t & 63;
    const int kq = (t >> 6) * 8;

    for (int c = 0; c < 18; ++c) {
        const int ab = c >> 1;
        const int al = ab / 3;
        const int be = ab % 3;
        const int ih = (c & 1) * 32;
        const int base = ih * 36864 + (h0 + 64 * al) * 192 + 64 * be + w0s;
#pragma unroll
        for (int s = 0; s < 8; ++s) {
            const int kp = kq + s;
            Xs[w0s][kp] = f2bf(xb[base + kp * 36864]);
        }
        __syncthreads();
        const int kb = c * 32 + lg * 8;
        short8 af[3];
#pragma unroll
        for (int mf = 0; mf < 3; ++mf)
            af[mf] = *(const short8*)(Wt + (wave_m0 + mf * 16 + lm) * 576 + kb);
        short8 bf[4];
#pragma unroll
        for (int pf = 0; pf < 4; ++pf) {
            union { short8 v; unsigned long long q[2]; } u;
            const unsigned long long* s8 =
                (const unsigned long long*)(&Xs[pf * 16 + lm][lg * 8]);
            u.q[0] = s8[0];
            u.q[1] = s8[1];
            bf[pf] = u.v;
        }
#pragma unroll
        for (int mf = 0; mf < 3; ++mf)
#pragma unroll
            for (int pf = 0; pf < 4; ++pf)
                acc[mf][pf] = __builtin_amdgcn_mfma_f32_16x16x32_bf16(
                    af[mf], bf[pf], acc[mf][pf], 0, 0, 0);
        __syncthreads();
    }

#pragma unroll
    for (int mf = 0; mf < 3; ++mf)
#pragma unroll
        for (int r = 0; r < 4; ++r) {
            const int m = wave_m0 + mf * 16 + lg * 4 + r;
            const int o = m & 63;
            const int ab2 = m >> 6;
            const float bo = bias[o];
            const int rowoff =
                ((n * 64 + o) * 192 + (h0 + 64 * (ab2 / 3))) * 192 + 64 * (ab2 % 3);
#pragma unroll
            for (int pf = 0; pf < 4; ++pf)
                out[rowoff + pf * 16 + lm] = acc[mf][pf][r] + bo;
        }
}

// ---------------------------------------------------------------------------
extern "C" void kernel_launch(void* const* d_in, const int* in_sizes, int n_in,
                              void* d_out, int out_size, void* d_ws, size_t ws_size,
                              hipStream_t stream) {
    (void)in_sizes; (void)n_in; (void)out_size;
    const float* x = (const float*)d_in[0];
    const float* W = (const float*)d_in[1];
    const float* bias = (const float*)d_in[2];
    const float* u0 = (const float*)d_in[3];
    float* out = (float*)d_out;

    float* Fm = (float*)d_ws;
    unsigned short* Wtf = (unsigned short*)((char*)d_ws + WTF_OFF);
    unsigned short* WtOld = (unsigned short*)((char*)d_ws + WTOLD_OFF);

    fm_kernel<<<5, 512, 0, stream>>>(W, u0, Fm);
    wbuild_kernel<<<16, 256, 0, stream>>>(Fm, Wtf, WtOld);

    if (ws_size >= WS_NEEDED) {
        gemm6_kernel<<<1536, 256, 0, stream>>>(x, Wtf, bias, out);
    } else {
        dim3 g(1024, 3, 1);
        gemm_fallback<<<g, 256, 0, stream>>>(x, WtOld, bias, out);
    }
}

// Round 10
// 111.424 us; speedup vs baseline: 1.8197x; 1.8197x over previous
//
#include <hip/hip_runtime.h>

typedef __attribute__((ext_vector_type(8))) short short8;
typedef __attribute__((ext_vector_type(4))) float f32x4;
typedef __attribute__((ext_vector_type(4))) float float4v;
typedef __attribute__((ext_vector_type(4))) unsigned int u32x4;

__device__ __forceinline__ unsigned short f2bf(float f) {
    unsigned int u = __float_as_uint(f);
    u += 0x7fffu + ((u >> 16) & 1u);
    return (unsigned short)(u >> 16);
}

__device__ __forceinline__ float wavesum(float x) {
#pragma unroll
    for (int m = 1; m < 64; m <<= 1) x += __shfl_xor(x, m);
    return x;
}

__device__ __forceinline__ float wavemax(float x) {
#pragma unroll
    for (int m = 1; m < 64; m <<= 1) x = fmaxf(x, __shfl_xor(x, m));
    return x;
}

// dot(row[0..63], y-distributed-one-per-lane) via readlane broadcasts.
__device__ __forceinline__ float matvec64(const float* row, float y) {
    float ac[8] = {0.f, 0.f, 0.f, 0.f, 0.f, 0.f, 0.f, 0.f};
#pragma unroll
    for (int j = 0; j < 64; ++j) {
        const float yj =
            __uint_as_float(__builtin_amdgcn_readlane(__float_as_uint(y), j));
        ac[j & 7] = fmaf(row[j], yj, ac[j & 7]);
    }
    return ((ac[0] + ac[1]) + (ac[2] + ac[3])) + ((ac[4] + ac[5]) + (ac[6] + ac[7]));
}

// async 16B global -> LDS (linear dest: wave-uniform base + lane*16)
__device__ __forceinline__ void gload16(const void* g, void* l) {
    __builtin_amdgcn_global_load_lds(
        (const __attribute__((address_space(1))) unsigned int*)g,
        (__attribute__((address_space(3))) unsigned int*)l, 16, 0, 0);
}

#define WTF_OFF       81920
#define WTOLD_OFF     745472
#define XT_OFF        1441792
#define WS_NEEDED     76939264UL

// fm LDS layout (bytes):
#define FM_AFP   0        // fp32 [64][68] = 17408
#define FM_R0    17408    // fp32 [64][68]
#define FM_R1    34816    // fp32 [64][68]
#define FM_SLOT  52224    // 3 slots x 4096 half (8192 B each) = 24576
#define FM_RED   76800    // 4 float wave-max + sigma
#define FM_SMEM  76928

// ---------------------------------------------------------------------------
// One 64x64x64 matmul on 4 waves (t<256), single-bf16 operands, fp32 acc.
// (Validated rounds 6-8.)
// ---------------------------------------------------------------------------
__device__ __forceinline__ void fm_matmul_sb(char* sm, int srcOff, int bfSrcSlot,
                                             int dstOff, int bfDstSlot, int t) {
    const float* src = (const float*)(sm + srcOff);
    const unsigned short* bfS =
        (const unsigned short*)(sm + FM_SLOT) + bfSrcSlot * 4096;
    float* dst = (float*)(sm + dstOff);
    float* redf = (float*)(sm + FM_RED);
    const int lane = t & 63;
    const int wv = t >> 6;
    const int lm = lane & 15, lg = lane >> 4;
    f32x4 acc[4] = {};
    if (t < 256) {
#pragma unroll
        for (int kk = 0; kk < 2; ++kk) {
            const float* ap = src + (16 * wv + lm) * 68 + kk * 32 + lg * 8;
            const f32x4 a0 = *(const f32x4*)ap;
            const f32x4 a1 = *(const f32x4*)(ap + 4);
            short8 ah;
#pragma unroll
            for (int j = 0; j < 4; ++j) {
                ah[j] = (short)f2bf(a0[j]);
                ah[j + 4] = (short)f2bf(a1[j]);
            }
#pragma unroll
            for (int cf = 0; cf < 4; ++cf) {
                const short8 b =
                    *(const short8*)(bfS + ((kk * 4 + cf) * 64 + lane) * 8);
                acc[cf] = __builtin_amdgcn_mfma_f32_16x16x32_bf16(ah, b, acc[cf],
                                                                  0, 0, 0);
            }
        }
        float mx = 0.0f;
#pragma unroll
        for (int cf = 0; cf < 4; ++cf)
#pragma unroll
            for (int r = 0; r < 4; ++r) mx = fmaxf(mx, fabsf(acc[cf][r]));
        mx = wavemax(mx);
        if (lane == 0) redf[wv] = mx;
    }
    __syncthreads();
    if (t < 256) {
        const float g = fmaxf(fmaxf(redf[0], redf[1]), fmaxf(redf[2], redf[3]));
        const float sc = 1.0f / g;
        unsigned short* bfD = (unsigned short*)(sm + FM_SLOT) + bfDstSlot * 4096;
#pragma unroll
        for (int cf = 0; cf < 4; ++cf) {
#pragma unroll
            for (int r = 0; r < 4; ++r) {
                const int k = 16 * wv + 4 * lg + r;
                const int nn = 16 * cf + lm;
                const float v = acc[cf][r] * sc;
                dst[k * 68 + nn] = v;
                if (bfDstSlot >= 0)
                    bfD[(((k >> 5) * 4 + cf) * 64 + ((k & 31) >> 3) * 16 + lm) * 8 +
                        (k & 7)] = f2bf(v);
            }
        }
    }
    __syncthreads();
}

// ---------------------------------------------------------------------------
// Fused: blocks 0..4 = fm (matrix-power sigma + MFMA bf16x3 Taylor);
//        blocks 5..1540 = barrier-free direct-gather x fp32 -> bf16 transpose
//        to xT[n][h][half][w][c32] (no LDS, 2-deep reg pipeline).
// ---------------------------------------------------------------------------
__global__ __launch_bounds__(512) void fmconv_kernel(const float* __restrict__ W,
                                                     const float* __restrict__ u0,
                                                     const float* __restrict__ x,
                                                     float* __restrict__ FmOut,
                                                     unsigned short* __restrict__ xT) {
    __shared__ __align__(16) char smem[FM_SMEM];
    const int t = threadIdx.x;

    if (blockIdx.x >= 5) {
        // ---- convert path: block = (n, hpair); half-block (256 thr) per h.
        // thread: w = tt>>2 (0..63), cg = tt&3; per subtile s=(half*3+wb):
        // 8 ch loads (64B-coalesced), pack bf16x8, one 16B store (wave-
        // contiguous 1KB). No barriers, no LDS.
        const int bb = blockIdx.x - 5;   // 0..1535
        const int n = bb / 96;
        const int hpair = bb % 96;
        const int h = hpair * 2 + (t >> 8);
        const int tt = t & 255;
        const int w = tt >> 2;           // 0..63
        const int cg = tt & 3;           // 0..3
        const size_t xbase = ((size_t)(n * 64) * 192 + h) * 192;
        unsigned short* xTrow = xT + ((size_t)((n * 192 + h) * 2)) * 6144;

        float A0[8], A1[8];
#define CLOAD(S, R)                                                             \
    {                                                                           \
        const int half_ = (S) / 3, wb_ = (S) % 3;                               \
        _Pragma("unroll") for (int k = 0; k < 8; ++k)                           \
            R[k] = x[xbase + (size_t)(half_ * 32 + cg * 8 + k) * 36864 +        \
                     wb_ * 64 + w];                                             \
    }
#define CSTORE(S, R)                                                            \
    {                                                                           \
        const int half_ = (S) / 3, wb_ = (S) % 3;                               \
        union { unsigned short us[8]; short8 v; } pk;                           \
        _Pragma("unroll") for (int k = 0; k < 8; ++k) pk.us[k] = f2bf(R[k]);    \
        *(short8*)(xTrow + half_ * 6144 + (wb_ * 64 + w) * 32 + cg * 8) = pk.v; \
    }
        CLOAD(0, A0);
        CLOAD(1, A1);
        CSTORE(0, A0);
        CLOAD(2, A0);
        CSTORE(1, A1);
        CLOAD(3, A1);
        CSTORE(2, A0);
        CLOAD(4, A0);
        CSTORE(3, A1);
        CLOAD(5, A1);
        CSTORE(4, A0);
        CSTORE(5, A1);
#undef CLOAD
#undef CSTORE
        return;
    }

    // ---- fm path (validated rounds 6-8) ----
    float* Afp = (float*)(smem + FM_AFP);
    float* R0f = (float*)(smem + FM_R0);
    float* R1f = (float*)(smem + FM_R1);
    float* redf = (float*)(smem + FM_RED);
    float* sigP = redf + 4;
    const int n = blockIdx.x;
    const int lane = t & 63;
    const int wv = t >> 6;
    const int lm = lane & 15, lg = lane >> 4;

    {
        const int i = t >> 3;
        const int j0 = (t & 7) * 8;
#pragma unroll
        for (int k = 0; k < 8; ++k) {
            const int j = j0 + k;
            const float wij = W[(i * 64 + j) * 5 + n];
            const float wji = W[(j * 64 + i) * 5 + n];
            Afp[i * 68 + j] = 0.5f * (wij - wji);
        }
    }
    __syncthreads();

    if (t < 256) {
        unsigned short* s0 = (unsigned short*)(smem + FM_SLOT);
#pragma unroll
        for (int cf = 0; cf < 4; ++cf) {
#pragma unroll
            for (int r = 0; r < 4; ++r) {
                const int k = 16 * wv + 4 * lg + r;
                const int nn = 16 * cf + lm;
                s0[(((k >> 5) * 4 + cf) * 64 + ((k & 31) >> 3) * 16 + lm) * 8 +
                   (k & 7)] = f2bf(Afp[k * 68 + nn]);
            }
        }
    }
    __syncthreads();

    fm_matmul_sb(smem, FM_AFP, 0, FM_R0, 1, t);  // M
    fm_matmul_sb(smem, FM_R0, 1, FM_R1, 2, t);   // M2
    fm_matmul_sb(smem, FM_R1, 2, FM_R0, 0, t);   // M4
    fm_matmul_sb(smem, FM_R0, 0, FM_R1, 2, t);   // M8
    fm_matmul_sb(smem, FM_R1, 2, FM_R0, 0, t);   // M16
    fm_matmul_sb(smem, FM_R0, 0, FM_R1, -1, t);  // M32
    fm_matmul_sb(smem, FM_R1, 0, FM_R0, -1, t);  // M48 = M32@M16
    fm_matmul_sb(smem, FM_R0, 1, FM_R1, -1, t);  // M49 = M48@M

    if (t < 64) {
        float row[64];
#pragma unroll
        for (int q = 0; q < 16; ++q)
            *(f32x4*)&row[q * 4] = *(const f32x4*)&R1f[t * 68 + q * 4];
        float u = u0[n * 64 + t];
        u = u / (sqrtf(wavesum(u * u)) + 1e-12f);
        const float w = matvec64(row, u);
#pragma unroll
        for (int q = 0; q < 16; ++q)
            *(f32x4*)&row[q * 4] = *(const f32x4*)&Afp[t * 68 + q * 4];
        const float tt = matvec64(row, w);
        const float v = tt / (sqrtf(wavesum(tt * tt)) + 1e-12f);
        const float s = matvec64(row, v);
        const float u50 = -s / (sqrtf(wavesum(s * s)) + 1e-12f);
        const float t2 = matvec64(row, u50);
        const float sig = wavesum(v * t2);
        if (t == 0) *sigP = sig;
    }
    __syncthreads();

    const float inv_sig = 1.0f / (*sigP);
    float Fm[4][4];
    if (t < 256) {
        unsigned int* Anpk = (unsigned int*)(smem + FM_SLOT);
#pragma unroll
        for (int cf = 0; cf < 4; ++cf) {
#pragma unroll
            for (int r = 0; r < 4; ++r) {
                const int k = 16 * wv + 4 * lg + r;
                const int nn = 16 * cf + lm;
                const float v = Afp[k * 68 + nn] * inv_sig;
                R0f[k * 68 + nn] = v;
                const unsigned int ph = f2bf(v);
                const float hf = __uint_as_float(ph << 16);
                const unsigned int pl = f2bf(v - hf);
                Anpk[(((k >> 5) * 4 + cf) * 64 + ((k & 31) >> 3) * 16 + lm) * 8 +
                     (k & 7)] = ph | (pl << 16);
                Fm[cf][r] = v;
            }
        }
    }
    __syncthreads();

    for (int term = 2; term <= 10; ++term) {
        f32x4 acc[4] = {};
        if (t < 256) {
            const unsigned int* Anpk = (const unsigned int*)(smem + FM_SLOT);
#pragma unroll
            for (int kk = 0; kk < 2; ++kk) {
                const float* ap = R0f + (16 * wv + lm) * 68 + kk * 32 + lg * 8;
                const f32x4 a0 = *(const f32x4*)ap;
                const f32x4 a1 = *(const f32x4*)(ap + 4);
                short8 ah, al;
#pragma unroll
                for (int j = 0; j < 4; ++j) {
                    const unsigned int h0 = f2bf(a0[j]);
                    ah[j] = (short)h0;
                    al[j] = (short)f2bf(a0[j] - __uint_as_float(h0 << 16));
                    const unsigned int h1 = f2bf(a1[j]);
                    ah[j + 4] = (short)h1;
                    al[j + 4] = (short)f2bf(a1[j] - __uint_as_float(h1 << 16));
                }
#pragma unroll
                for (int cf = 0; cf < 4; ++cf) {
                    const unsigned int* pp = Anpk + ((kk * 4 + cf) * 64 + lane) * 8;
                    const u32x4 p0 = *(const u32x4*)pp;
                    const u32x4 p1 = *(const u32x4*)(pp + 4);
                    short8 bh, bl;
#pragma unroll
                    for (int j = 0; j < 4; ++j) {
                        bh[j] = (short)(p0[j] & 0xffffu);
                        bl[j] = (short)(p0[j] >> 16);
                        bh[j + 4] = (short)(p1[j] & 0xffffu);
                        bl[j + 4] = (short)(p1[j] >> 16);
                    }
                    acc[cf] = __builtin_amdgcn_mfma_f32_16x16x32_bf16(ah, bh,
                                                                      acc[cf], 0, 0, 0);
                    acc[cf] = __builtin_amdgcn_mfma_f32_16x16x32_bf16(ah, bl,
                                                                      acc[cf], 0, 0, 0);
                    acc[cf] = __builtin_amdgcn_mfma_f32_16x16x32_bf16(al, bh,
                                                                      acc[cf], 0, 0, 0);
                }
            }
        }
        __syncthreads();
        if (t < 256) {
            const float sc = 1.0f / (float)term;
#pragma unroll
            for (int cf = 0; cf < 4; ++cf) {
#pragma unroll
                for (int r = 0; r < 4; ++r) {
                    const int k = 16 * wv + 4 * lg + r;
                    const int nn = 16 * cf + lm;
                    const float v = acc[cf][r] * sc;
                    Fm[cf][r] += v;
                    if (term < 10) R0f[k * 68 + nn] = v;
                }
            }
        }
        __syncthreads();
    }

    if (t < 256) {
#pragma unroll
        for (int cf = 0; cf < 4; ++cf) {
#pragma unroll
            for (int r = 0; r < 4; ++r) {
                const int k = 16 * wv + 4 * lg + r;
                const int nn = 16 * cf + lm;
                FmOut[n * 4096 + k * 64 + nn] = Fm[cf][r] + ((k == nn) ? 1.0f : 0.0f);
            }
        }
    }
}

// ---------------------------------------------------------------------------
// wbuild: Fm -> 3x3 real-ifft -> folded weight; Wtf (16x16 A-frag order) and
// WtOld ([m][kap]) for the fallback path. (Unchanged.)
// ---------------------------------------------------------------------------
__global__ __launch_bounds__(256) void wbuild_kernel(const float* __restrict__ Fm,
                                                     unsigned short* __restrict__ Wtf,
                                                     unsigned short* __restrict__ WtOld) {
    const int tg = blockIdx.x * 256 + threadIdx.x;
    const int o = tg >> 6;
    const int i = tg & 63;
    float f[5];
#pragma unroll
    for (int nn = 0; nn < 5; ++nn) f[nn] = Fm[nn * 4096 + o * 64 + i];
    const int idx[3][3] = {{0, 1, 1}, {2, 3, 4}, {2, 4, 3}};
    float Kk[3][3];
#pragma unroll
    for (int u = 0; u < 3; ++u) {
#pragma unroll
        for (int v = 0; v < 3; ++v) {
            float s = 0.0f;
#pragma unroll
            for (int p = 0; p < 3; ++p) {
#pragma unroll
                for (int q = 0; q < 3; ++q) {
                    const int m = (p * u + q * v) % 3;
                    s += f[idx[p][q]] * ((m == 0) ? 1.0f : -0.5f);
                }
            }
            Kk[u][v] = s * (1.0f / 9.0f);
        }
    }
#pragma unroll
    for (int a = 0; a < 3; ++a) {
#pragma unroll
        for (int b = 0; b < 3; ++b) {
            const int m = (a * 3 + b) * 64 + o;
#pragma unroll
            for (int al = 0; al < 3; ++al) {
#pragma unroll
                for (int be = 0; be < 3; ++be) {
                    const int kh = (al - a + 4) % 3;
                    const int kw = (be - b + 4) % 3;
                    const unsigned short bf = f2bf(Kk[kh][kw]);
                    const int kap = (al * 3 + be) * 64 + i;
                    WtOld[m * 576 + kap] = bf;
                    const int MF = m >> 4, lmx = m & 15;
                    const int cc = kap >> 5, lgx = (kap >> 3) & 3, j = kap & 7;
                    Wtf[MF * 9216 + cc * 512 + (lgx * 16 + lmx) * 8 + j] = bf;
                }
            }
        }
    }
}

// ---------------------------------------------------------------------------
// gemm4: LDS double-buffered, staged via global_load_lds x16B from Wtf + xT.
// (Validated rounds 4-6: ~45 us, zero bank conflicts.)
// ---------------------------------------------------------------------------
__global__ __launch_bounds__(256, 2) void gemm4_kernel(
    const unsigned short* __restrict__ xT, const unsigned short* __restrict__ Wtf,
    const float* __restrict__ bias, float* __restrict__ out) {
    __shared__ __align__(16) char smem[81920];
    const int t = threadIdx.x;
    const int lane = t & 63;
    const int wv = t >> 6;
    const int wm = wv >> 1;
    const int wp = wv & 1;
    const int lm = lane & 15;
    const int lg = lane >> 4;

    const int orig = blockIdx.x;
    const int swz = (orig & 7) * 192 + (orig >> 3);
    const int mg = swz % 3;
    const int panel = swz / 3;
    const int n = panel >> 5;
    const int h0b = (panel & 31) * 2;

    f32x4 acc[6][4] = {};

#define STAGE(BUF, KC)                                                          \
    {                                                                           \
        const int al_ = (KC) / 3, be_ = (KC) - 3 * ((KC) / 3);                  \
        _Pragma("unroll") for (int it = 0; it < 10; ++it) {                     \
            char* ldsb = smem + (BUF) * 40960 + it * 4096 + wv * 1024;          \
            const unsigned short* src;                                          \
            if (it < 6) {                                                       \
                const int e = it * 2048 + t * 8;                                \
                const int mfL = e >> 10;                                        \
                const int rem = e & 1023;                                       \
                src = Wtf + (mg * 12 + mfL) * 9216 + (KC) * 1024 + rem;         \
            } else {                                                            \
                const int e = (it - 6) * 2048 + t * 8;                          \
                const int ccL = e >> 12;                                        \
                const int rem = e & 4095;                                       \
                const int p_ = rem >> 5;                                        \
                const int c_ = rem & 31;                                        \
                const int h_ = h0b + (p_ >> 6) + 64 * al_;                      \
                const int w_ = be_ * 64 + (p_ & 63);                            \
                src = xT + ((size_t)((n * 192 + h_) * 2 + ccL)) * 6144 +        \
                      w_ * 32 + c_;                                             \
            }                                                                   \
            gload16(src, ldsb);                                                 \
        }                                                                       \
    }

#define COMPUTE(BUF)                                                            \
    {                                                                           \
        const char* base = smem + (BUF) * 40960;                                \
        short8 af[12];                                                          \
        short8 bf[8];                                                           \
        _Pragma("unroll") for (int mf = 0; mf < 6; ++mf)                        \
            _Pragma("unroll") for (int cl = 0; cl < 2; ++cl)                    \
                af[mf * 2 + cl] = *(const short8*)(                             \
                    base + (wm * 6 + mf) * 2048 + cl * 1024 + lane * 16);       \
        _Pragma("unroll") for (int pf = 0; pf < 4; ++pf)                        \
            _Pragma("unroll") for (int cl = 0; cl < 2; ++cl)                    \
                bf[pf * 2 + cl] = *(const short8*)(                             \
                    base + 24576 + cl * 8192 +                                  \
                    (wp * 64 + pf * 16 + lm) * 64 + lg * 16);                   \
        _Pragma("unroll") for (int cl = 0; cl < 2; ++cl)                        \
            _Pragma("unroll") for (int mf = 0; mf < 6; ++mf)                    \
                _Pragma("unroll") for (int pf = 0; pf < 4; ++pf)                \
                    acc[mf][pf] = __builtin_amdgcn_mfma_f32_16x16x32_bf16(      \
                        af[mf * 2 + cl], bf[pf * 2 + cl], acc[mf][pf], 0, 0, 0);\
    }

    STAGE(0, 0);
    __syncthreads();
#pragma unroll
    for (int kc = 0; kc < 9; ++kc) {
        const int b = kc & 1;
        if (kc < 8) STAGE(b ^ 1, kc + 1);
        COMPUTE(b);
        if (kc < 8) __syncthreads();
    }
#undef STAGE
#undef COMPUTE

    const int h0 = h0b + wp;
#pragma unroll
    for (int mf = 0; mf < 6; ++mf) {
#pragma unroll
        for (int r = 0; r < 4; ++r) {
            const int m = mg * 192 + wm * 96 + mf * 16 + lg * 4 + r;
            const int o = m & 63;
            const int ab2 = m >> 6;
            const float bo = bias[o];
            const int rowoff =
                ((n * 64 + o) * 192 + (h0 + 64 * (ab2 / 3))) * 192 + 64 * (ab2 % 3);
#pragma unroll
            for (int pf = 0; pf < 4; ++pf) {
                out[rowoff + pf * 16 + lm] = acc[mf][pf][r] + bo;
            }
        }
    }
}

// ---------------------------------------------------------------------------
// Fallback GEMM (round-1 validated, LDS-staged fp32) if ws too small for xT.
// ---------------------------------------------------------------------------
__global__ __launch_bounds__(256) void gemm_fallback(const float* __restrict__ x,
                                                     const unsigned short* __restrict__ Wt,
                                                     const float* __restrict__ bias,
                                                     float* __restrict__ out) {
    __shared__ unsigned short Xs[64][36];
    const int t = threadIdx.x;
    const int lane = t & 63;
    const int wv = t >> 6;
    const int pblk = blockIdx.x;
    const int mg = blockIdx.y;
    const int n = pblk >> 6;
    const int h0 = pblk & 63;
    const int wave_m0 = mg * 192 + wv * 48;
    const int lm = lane & 15;
    const int lg = lane >> 4;

    f32x4 acc[3][4] = {};
    const float* xb = x + n * 64 * 36864;
    const int w0s = t & 63;
    const int kq = (t >> 6) * 8;

    for (int c = 0; c < 18; ++c) {
        const int ab = c >> 1;
        const int al = ab / 3;
        const int be = ab % 3;
        const int ih = (c & 1) * 32;
        const int base = ih * 36864 + (h0 + 64 * al) * 192 + 64 * be + w0s;
#pragma unroll
        for (int s = 0; s < 8; ++s) {
            const int kp = kq + s;
            Xs[w0s][kp] = f2bf(xb[base + kp * 36864]);
        }
        __syncthreads();
        const int kb = c * 32 + lg * 8;
        short8 af[3];
#pragma unroll
        for (int mf = 0; mf < 3; ++mf)
            af[mf] = *(const short8*)(Wt + (wave_m0 + mf * 16 + lm) * 576 + kb);
        short8 bf[4];
#pragma unroll
        for (int pf = 0; pf < 4; ++pf) {
            union { short8 v; unsigned long long q[2]; } u;
            const unsigned long long* s8 =
                (const unsigned long long*)(&Xs[pf * 16 + lm][lg * 8]);
            u.q[0] = s8[0];
            u.q[1] = s8[1];
            bf[pf] = u.v;
        }
#pragma unroll
        for (int mf = 0; mf < 3; ++mf)
#pragma unroll
            for (int pf = 0; pf < 4; ++pf)
                acc[mf][pf] = __builtin_amdgcn_mfma_f32_16x16x32_bf16(
                    af[mf], bf[pf], acc[mf][pf], 0, 0, 0);
        __syncthreads();
    }

#pragma unroll
    for (int mf = 0; mf < 3; ++mf)
#pragma unroll
        for (int r = 0; r < 4; ++r) {
            const int m = wave_m0 + mf * 16 + lg * 4 + r;
            const int o = m & 63;
            const int ab2 = m >> 6;
            const float bo = bias[o];
            const int rowoff =
                ((n * 64 + o) * 192 + (h0 + 64 * (ab2 / 3))) * 192 + 64 * (ab2 % 3);
#pragma unroll
            for (int pf = 0; pf < 4; ++pf)
                out[rowoff + pf * 16 + lm] = acc[mf][pf][r] + bo;
        }
}

// ---------------------------------------------------------------------------
extern "C" void kernel_launch(void* const* d_in, const int* in_sizes, int n_in,
                              void* d_out, int out_size, void* d_ws, size_t ws_size,
                              hipStream_t stream) {
    (void)in_sizes; (void)n_in; (void)out_size;
    const float* x = (const float*)d_in[0];
    const float* W = (const float*)d_in[1];
    const float* bias = (const float*)d_in[2];
    const float* u0 = (const float*)d_in[3];
    float* out = (float*)d_out;

    float* Fm = (float*)d_ws;
    unsigned short* Wtf = (unsigned short*)((char*)d_ws + WTF_OFF);
    unsigned short* WtOld = (unsigned short*)((char*)d_ws + WTOLD_OFF);
    unsigned short* xT = (unsigned short*)((char*)d_ws + XT_OFF);

    const bool big_ws = (ws_size >= WS_NEEDED);

    if (big_ws) {
        fmconv_kernel<<<5 + 1536, 512, 0, stream>>>(W, u0, x, Fm, xT);
        wbuild_kernel<<<16, 256, 0, stream>>>(Fm, Wtf, WtOld);
        gemm4_kernel<<<1536, 256, 0, stream>>>(xT, Wtf, bias, out);
    } else {
        fmconv_kernel<<<5, 512, 0, stream>>>(W, u0, x, Fm, xT);
        wbuild_kernel<<<16, 256, 0, stream>>>(Fm, Wtf, WtOld);
        dim3 g(1024, 3, 1);
        gemm_fallback<<<g, 256, 0, stream>>>(x, WtOld, bias, out);
    }
}